// Round 21
// baseline (101.874 us; speedup 1.0000x reference)
//
#include <hip/hip_runtime.h>

// QuantizedConv1d on MI355X (gfx950) — round 21: producer/consumer waves
// B=32, CIN=128, L=4096, COUT=256, K=5, replication pad 2.
//   wprep_kernel: W int32 -> fragment-linear i8 wtf[160][64][16B] + tbl (tiny)
//   conv_fused:   768 thr = 12 waves, 1 block/CU (grid 256, persistent over
//                 4 x 128-l tiles, dbuf LDS 2x17.4KB).
//                 Waves 0-7 CONSUMERS: r15-verified K-loop + epilogue
//                 (acc[4][4], no staging state, ~110 VGPR).
//                 Waves 8-11 PRODUCERS: load+quant+ds_write tile t+1 only
//                 (~55 VGPR). One barrier per phase: x-read overlaps
//                 out-write + MFMA by construction.
// Round 15-20 box: lockstep phases never overlap (2 blocks/CU, reg-capped);
// r19's all-wave pipeline spilled. Role split gives overlap without spill.

#define B_    32
#define CIN   128
#define LEN   4096
#define COUT  256
#define KW    5
#define TROWS 136        // rows per staged tile: gl in [Lt-4, Lt+131]
#define NT    4          // tiles per block (4 x 128 l = 512 l)
#define LDS_TILE 17408   // 136 rows x 128 B

#define WTF_BYTES (KW * 2 * 16 * 64 * 16)   // 163,840

typedef int          i32x4 __attribute__((ext_vector_type(4)));
typedef signed char  s8;

// round-half-even(x*20 - 3), clip to [-128,127], as int8.
// (fmaf fold vs round(x/0.05)+(-3): ~1e-6 tie flips, <=1 output step each;
// absmax has been 1.0 vs threshold 2.56 since r6.)
__device__ __forceinline__ s8 quant_i8(float xv) {
    float q = rintf(fmaf(xv, 20.0f, -3.0f));
    q = fminf(fmaxf(q, -128.0f), 127.0f);
    return (s8)(int)q;
}

// W -> fragment-linear i8: frag = k*32 + s*16 + co16; lane holds
// W[co16*16 + (lane&15)][ci = s*64 + (lane>>4)*16 + j], j=0..15.
__global__ __launch_bounds__(256) void wprep_kernel(
        const int* __restrict__ w, const int* __restrict__ bias,
        const float* __restrict__ wscale,
        s8* __restrict__ wtf, float* __restrict__ tbl)
{
    int o    = blockIdx.x * 256 + threadIdx.x;   // 0..10239
    int lane = o & 63, frag = o >> 6;            // frag 0..159
    int k    = frag >> 5;
    int s    = (frag >> 4) & 1;
    int co   = ((frag & 15) << 4) + (lane & 15);
    int ci   = (s << 6) + ((lane >> 4) << 4);
    union { s8 c[16]; i32x4 v; } q;
    #pragma unroll
    for (int j = 0; j < 16; ++j)
        q.c[j] = (s8)w[co * (CIN * KW) + (ci + j) * KW + k];   // |v|<=127
    *(i32x4*)(wtf + (size_t)frag * 1024 + lane * 16) = q.v;

    if (blockIdx.x == 0) {                        // requant table: sc, off
        int c = threadIdx.x;                      // 0..255
        float sc = __fdiv_rn(__fmul_rn(0.05f, wscale[c]), 0.1f);
        tbl[c]       = sc;
        tbl[256 + c] = fmaf((float)bias[c], sc, -128.0f);
    }
}

// Stage one 16-ci chunk c of the tile at Lt into buf (rows lane, 64+lane,
// 128+lane for lane<8); swizzle chunk ^= (row&7) — 0 conflicts (r10-12).
__device__ __forceinline__ void stage_chunk(
        const float* __restrict__ xb, s8* __restrict__ buf,
        int Lt, int c, int lane)
{
    const float* src = xb + (size_t)(c << 4) * LEN;
    int gl0 = min(max(Lt - 4 + lane, 0), LEN - 1);
    int gl1 = min(max(Lt + 60 + lane, 0), LEN - 1);
    float v0[16], v1[16];
    #pragma unroll
    for (int j = 0; j < 16; ++j) {
        v0[j] = src[(size_t)j * LEN + gl0];
        v1[j] = src[(size_t)j * LEN + gl1];
    }
    union { s8 cc[16]; i32x4 v; } q0, q1;
    #pragma unroll
    for (int j = 0; j < 16; ++j) q0.cc[j] = quant_i8(v0[j]);
    #pragma unroll
    for (int j = 0; j < 16; ++j) q1.cc[j] = quant_i8(v1[j]);
    int row0 = lane, row1 = 64 + lane;
    *(i32x4*)(buf + (row0 << 7) + ((c ^ (row0 & 7)) << 4)) = q0.v;
    *(i32x4*)(buf + (row1 << 7) + ((c ^ (row1 & 7)) << 4)) = q1.v;
    if (lane < 8) {                    // tail rows 128..135
        int row2 = 128 + lane;
        int gl2 = min(max(Lt + 124 + lane, 0), LEN - 1);
        union { s8 cc[16]; i32x4 v; } q2;
        #pragma unroll
        for (int j = 0; j < 16; ++j)
            q2.cc[j] = quant_i8(src[(size_t)j * LEN + gl2]);
        *(i32x4*)(buf + (row2 << 7) + ((c ^ (row2 & 7)) << 4)) = q2.v;
    }
}

// Block: persistent over 4 tiles of 256co x 128l. 12 waves:
//   consumers (0-7): 4co x 2l grid, wave = 64co x 64l, acc[4][4] — r15 code.
//   producers (8-11): 2 chunks each (pw, pw+4) of next tile.
// Grid 256 = B(32) x lseg(8), XCD-chunked bijective remap (256 = 8 x 32).
__global__ __launch_bounds__(768, 3) void conv_fused(
        const float* __restrict__ x, const s8* __restrict__ wtf,
        const float* __restrict__ tbl, int* __restrict__ out)
{
    __shared__ __align__(16) s8 smem[2 * LDS_TILE];   // 34,816 B

    int orig = (blockIdx.x & 7) * 32 + (blockIdx.x >> 3);
    int lseg = orig & 7;
    int b    = orig >> 3;
    int L0   = lseg << 9;              // 512 l per block
    int tid  = threadIdx.x;
    int wid  = tid >> 6, lane = tid & 63;
    int lr   = lane & 15, lh = lane >> 4;

    const float* xb = x + (size_t)b * CIN * LEN;

    // ---- prologue: consumers (8 waves, chunk = wid) stage tile 0 ----
    if (wid < 8)
        stage_chunk(xb, smem, L0, wid, lane);
    __syncthreads();

    size_t outb = (size_t)b * COUT * LEN;

    if (wid < 8) {
        // ================= CONSUMERS =================
        int cog = (wid & 3) << 6;          // wave co base: 4 x 64
        int wl  = (wid >> 2) << 6;         // wave local-l base {0, 64}
        // hoisted per-lane requant constants
        float scv[4], offv[4];
        #pragma unroll
        for (int ct = 0; ct < 4; ++ct) {
            scv[ct]  = tbl[cog + (ct << 4) + lr];
            offv[ct] = tbl[256 + cog + (ct << 4) + lr];
        }
        for (int t = 0; t < NT; ++t) {
            const s8* buf = smem + (t & 1) * LDS_TILE;
            int l0 = L0 + (t << 7);

            // K-loop: 5 taps x 2 ci-halves; 4 af (1KB coalesced, L2) +
            // 4 bf (conflict-free b128) -> 16 mfma_i32_16x16x64_i8.
            // SWAPPED operands (A=X row=l, B=W col=co): D col=co, row=l.
            i32x4 acc[4][4] = {};
            #pragma unroll
            for (int k = 0; k < KW; ++k) {
                #pragma unroll
                for (int s = 0; s < 2; ++s) {
                    i32x4 af[4];
                    #pragma unroll
                    for (int ct = 0; ct < 4; ++ct)
                        af[ct] = *(const i32x4*)(
                            wtf + (size_t)((k << 5) + (s << 4) + (cog >> 4) + ct) * 1024 + lane * 16);
                    i32x4 bf[4];
                    int chunk = (s << 2) + lh;
                    #pragma unroll
                    for (int lt = 0; lt < 4; ++lt) {
                        int row = wl + (lt << 4) + lr + k + 2;
                        bf[lt] = *(const i32x4*)(buf + (row << 7) + ((chunk ^ (row & 7)) << 4));
                    }
                    #pragma unroll
                    for (int ct = 0; ct < 4; ++ct)
                        #pragma unroll
                        for (int lt = 0; lt < 4; ++lt)
                            acc[ct][lt] = __builtin_amdgcn_mfma_i32_16x16x64_i8(
                                bf[lt], af[ct], acc[ct][lt], 0, 0, 0);
                }
            }

            // epilogue: col=co (per-lane sc/off), row=l; dwordx4 stores.
            #pragma unroll
            for (int ct = 0; ct < 4; ++ct) {
                int co = cog + (ct << 4) + lr;
                int* orow = out + outb + (size_t)co * LEN + l0 + wl + (lh << 2);
                #pragma unroll
                for (int lt = 0; lt < 4; ++lt) {
                    i32x4 pk;
                    #pragma unroll
                    for (int r = 0; r < 4; ++r) {
                        float o = rintf(fmaf((float)acc[ct][lt][r], scv[ct], offv[ct]));
                        o = fminf(fmaxf(o, -128.0f), 127.0f);
                        pk[r] = (int)o;
                    }
                    *(i32x4*)(orow + (lt << 4)) = pk;
                }
            }
            __syncthreads();
        }
    } else {
        // ================= PRODUCERS =================
        int pw = wid - 8;                   // 0..3, owns chunks pw and pw+4
        for (int t = 0; t < NT; ++t) {
            if (t + 1 < NT) {
                s8* nbuf = smem + ((t + 1) & 1) * LDS_TILE;
                int Ln = L0 + ((t + 1) << 7);
                stage_chunk(xb, nbuf, Ln, pw, lane);
                stage_chunk(xb, nbuf, Ln, pw + 4, lane);
            }
            __syncthreads();
        }
    }
}

extern "C" void kernel_launch(void* const* d_in, const int* in_sizes, int n_in,
                              void* d_out, int out_size, void* d_ws, size_t ws_size,
                              hipStream_t stream)
{
    const float* x    = (const float*)d_in[0];
    const int*   w    = (const int*)d_in[1];
    const int*   bias = (const int*)d_in[2];
    const float* wsc  = (const float*)d_in[3];
    int* out = (int*)d_out;

    s8*    wtf = (s8*)d_ws;                         // 163,840 B
    float* tbl = (float*)((char*)d_ws + WTF_BYTES); // +2 KB

    wprep_kernel<<<dim3(40), dim3(256), 0, stream>>>(w, bias, wsc, wtf, tbl);
    conv_fused<<<dim3(256), dim3(768), 0, stream>>>(x, wtf, tbl, out);
}

// Round 22
// 54.986 us; speedup vs baseline: 1.8527x; 1.8527x over previous
//
#include <hip/hip_runtime.h>

// QuantizedConv1d on MI355X (gfx950) — FINAL (= round-15/20 best, 55.0 us)
// B=32, CIN=128, L=4096, COUT=256, K=5, replication pad 2.
//   wprep_kernel: W int32 -> fragment-linear i8 wtf[160][64][16B] + tbl (tiny)
//   conv_fused:   block = 256co x 128l, 512 thr, 8 waves = 4co x 2l,
//                 wave = 64co x 64l (acc[4][4]). Staging: all 32 main loads
//                 issued upfront (static reg arrays), then quant+write, then
//                 8-lane tail. Swizzled LDS (0 conflicts measured), i8 MFMA
//                 swapped operands (verified layout), dwordx4 epilogue
//                 (WRITE_SIZE exactly ideal).
// Probes r13/r16 (smaller tiles), r17 (LDS-free), r18 (nt+setprio),
// r19/r21 (pipelines: spill) all regressed — this structure is the
// measured plain-HIP optimum for this op on this chip.

#define B_    32
#define CIN   128
#define LEN   4096
#define COUT  256
#define KW    5
#define TROWS 136   // staged rows: gl in [l0-4, l0+131]

#define WTF_BYTES (KW * 2 * 16 * 64 * 16)   // 163,840

typedef int          i32x4 __attribute__((ext_vector_type(4)));
typedef signed char  s8;

// round-half-even(x*20 - 3), clip to [-128,127], as int8.
// fmaf fold: differs from round(x/0.05)+(-3) only on ~1e-6 tie flips, each
// moving an output by <=1 step — absmax has been 1.0 (threshold 2.56) since r6.
__device__ __forceinline__ s8 quant_i8(float xv) {
    float q = rintf(fmaf(xv, 20.0f, -3.0f));
    q = fminf(fmaxf(q, -128.0f), 127.0f);
    return (s8)(int)q;
}

// W -> fragment-linear i8: frag = k*32 + s*16 + co16; lane holds
// W[co16*16 + (lane&15)][ci = s*64 + (lane>>4)*16 + j], j=0..15.
__global__ __launch_bounds__(256) void wprep_kernel(
        const int* __restrict__ w, const int* __restrict__ bias,
        const float* __restrict__ wscale,
        s8* __restrict__ wtf, float* __restrict__ tbl)
{
    int o    = blockIdx.x * 256 + threadIdx.x;   // 0..10239
    int lane = o & 63, frag = o >> 6;            // frag 0..159
    int k    = frag >> 5;
    int s    = (frag >> 4) & 1;
    int co   = ((frag & 15) << 4) + (lane & 15);
    int ci   = (s << 6) + ((lane >> 4) << 4);
    union { s8 c[16]; i32x4 v; } q;
    #pragma unroll
    for (int j = 0; j < 16; ++j)
        q.c[j] = (s8)w[co * (CIN * KW) + (ci + j) * KW + k];   // |v|<=127
    *(i32x4*)(wtf + (size_t)frag * 1024 + lane * 16) = q.v;

    if (blockIdx.x == 0) {                        // requant table: sc, off
        int c = threadIdx.x;                      // 0..255
        float sc = __fdiv_rn(__fmul_rn(0.05f, wscale[c]), 0.1f);
        tbl[c]       = sc;
        tbl[256 + c] = fmaf((float)bias[c], sc, -128.0f);
    }
}

// Block: 256 co x 128 l, 512 threads, 8 waves = 4 co-waves x 2 l-waves.
// Wave = 64co x 64l, acc[4][4]. LDS: [136 rows][128 ci] i8, 17,408 B,
// swizzle: 16B-chunk ^= (row & 7) — measured 0 conflicts (r10-12).
// launch_bounds(512,4): 128-reg cap, 2 blocks/CU = 16 waves.
// Grid 1024 = B(32) x ltile(32), XCD-chunked bijective remap (1024 = 8x128).
__global__ __launch_bounds__(512, 4) void conv_fused(
        const float* __restrict__ x, const s8* __restrict__ wtf,
        const float* __restrict__ tbl, int* __restrict__ out)
{
    __shared__ __align__(16) s8 smem[TROWS * CIN];   // 17,408 B

    int orig  = (blockIdx.x & 7) * 128 + (blockIdx.x >> 3);
    int ltile = orig & 31;
    int b     = orig >> 5;
    int l0    = ltile << 7;
    int tid   = threadIdx.x;
    int wid   = tid >> 6, lane = tid & 63;
    int lr    = lane & 15, lh = lane >> 4;
    int cog   = (wid & 3) << 6;          // wave co base: 4 x 64
    int wl    = (wid >> 2) << 6;         // wave local-l base {0, 64}

    const float* xb = x + (size_t)b * CIN * LEN;

    // ---- stage: quantize + transpose rows [l0-4, l0+131] (clamped) ----
    // Wave wid owns ci-chunk c = wid (16 ci). Rows: lane, 64+lane, 128+lane(<8).
    // All 32 main loads issued upfront -> one HBM-latency wait, not three.
    {
        const float* src = xb + (size_t)(wid << 4) * LEN;
        int gl0 = min(max(l0 - 4 + lane, 0), LEN - 1);
        int gl1 = min(max(l0 + 60 + lane, 0), LEN - 1);
        float v0[16], v1[16];
        #pragma unroll
        for (int j = 0; j < 16; ++j) {
            v0[j] = src[(size_t)j * LEN + gl0];
            v1[j] = src[(size_t)j * LEN + gl1];
        }
        union { s8 cc[16]; i32x4 v; } q0, q1;
        #pragma unroll
        for (int j = 0; j < 16; ++j) q0.cc[j] = quant_i8(v0[j]);
        #pragma unroll
        for (int j = 0; j < 16; ++j) q1.cc[j] = quant_i8(v1[j]);
        int row0 = lane, row1 = 64 + lane;
        *(i32x4*)(smem + (row0 << 7) + ((wid ^ (row0 & 7)) << 4)) = q0.v;
        *(i32x4*)(smem + (row1 << 7) + ((wid ^ (row1 & 7)) << 4)) = q1.v;
        if (lane < 8) {                    // tail rows 128..135
            int row2 = 128 + lane;
            int gl2 = min(max(l0 + 124 + lane, 0), LEN - 1);
            union { s8 cc[16]; i32x4 v; } q2;
            #pragma unroll
            for (int j = 0; j < 16; ++j)
                q2.cc[j] = quant_i8(src[(size_t)j * LEN + gl2]);
            *(i32x4*)(smem + (row2 << 7) + ((wid ^ (row2 & 7)) << 4)) = q2.v;
        }
    }
    __syncthreads();

    // ---- K-loop: 5 taps x 2 ci-halves; 4 af (1KB coalesced, L2-resident) +
    // 4 bf (conflict-free b128) -> 16 mfma_i32_16x16x64_i8.
    // SWAPPED operands (A=X row=l, B=W col=co): D col=co, row=l.
    i32x4 acc[4][4] = {};
    #pragma unroll
    for (int k = 0; k < KW; ++k) {
        #pragma unroll
        for (int s = 0; s < 2; ++s) {
            i32x4 af[4];
            #pragma unroll
            for (int ct = 0; ct < 4; ++ct)
                af[ct] = *(const i32x4*)(
                    wtf + (size_t)((k << 5) + (s << 4) + (cog >> 4) + ct) * 1024 + lane * 16);
            i32x4 bf[4];
            int chunk = (s << 2) + lh;
            #pragma unroll
            for (int lt = 0; lt < 4; ++lt) {
                int row = wl + (lt << 4) + lr + k + 2;
                bf[lt] = *(const i32x4*)(smem + (row << 7) + ((chunk ^ (row & 7)) << 4));
            }
            #pragma unroll
            for (int ct = 0; ct < 4; ++ct)
                #pragma unroll
                for (int lt = 0; lt < 4; ++lt)
                    acc[ct][lt] = __builtin_amdgcn_mfma_i32_16x16x64_i8(
                        bf[lt], af[ct], acc[ct][lt], 0, 0, 0);
        }
    }

    // ---- requant epilogue: col=co=cog+ct*16+lr (per-lane sc/off), row=l.
    // acc[ct][lt] = 4 consecutive l at fixed co -> one dwordx4 store each.
    // (float)int32 is exact (|sum| <= 10.3M < 2^24).
    size_t outb = (size_t)b * COUT * LEN;
    #pragma unroll
    for (int ct = 0; ct < 4; ++ct) {
        int co = cog + (ct << 4) + lr;
        float scv = tbl[co];
        float off = tbl[256 + co];
        int* orow = out + outb + (size_t)co * LEN + l0 + wl + (lh << 2);
        #pragma unroll
        for (int lt = 0; lt < 4; ++lt) {
            i32x4 pk;
            #pragma unroll
            for (int r = 0; r < 4; ++r) {
                float o = rintf(fmaf((float)acc[ct][lt][r], scv, off));
                o = fminf(fmaxf(o, -128.0f), 127.0f);
                pk[r] = (int)o;
            }
            *(i32x4*)(orow + (lt << 4)) = pk;
        }
    }
}

extern "C" void kernel_launch(void* const* d_in, const int* in_sizes, int n_in,
                              void* d_out, int out_size, void* d_ws, size_t ws_size,
                              hipStream_t stream)
{
    const float* x    = (const float*)d_in[0];
    const int*   w    = (const int*)d_in[1];
    const int*   bias = (const int*)d_in[2];
    const float* wsc  = (const float*)d_in[3];
    int* out = (int*)d_out;

    s8*    wtf = (s8*)d_ws;                         // 163,840 B
    float* tbl = (float*)((char*)d_ws + WTF_BYTES); // +2 KB

    wprep_kernel<<<dim3(40), dim3(256), 0, stream>>>(w, bias, wsc, wtf, tbl);
    conv_fused<<<dim3(1024), dim3(512), 0, stream>>>(x, wtf, tbl, out);
}